// Round 4
// baseline (4753.675 us; speedup 1.0000x reference)
//
#include <hip/hip_runtime.h>
#include <math.h>

#define T_STEPS 2048
#define HID     128
#define G4      512   // 4*H

typedef _Float16 half8 __attribute__((ext_vector_type(8)));
typedef float    f32x4 __attribute__((ext_vector_type(4)));

__device__ __forceinline__ float fast_sig(float x) {
    return __fdividef(1.0f, 1.0f + __expf(-x));
}
__device__ __forceinline__ float fast_tanh(float x) {
    return fmaf(2.0f, __fdividef(1.0f, 1.0f + __expf(-2.0f * x)), -1.0f);
}
__device__ __forceinline__ f32x4 ld4(const float* p) {
    float4 v = *reinterpret_cast<const float4*>(p);
    f32x4 r; r[0] = v.x; r[1] = v.y; r[2] = v.z; r[3] = v.w; return r;
}

// ---------------------------------------------------------------------------
// MFMA LSTM recurrence, single live batch element (b = 127).
// ROUND-3 LESSON: neither __launch_bounds__(.,2) nor amdgpu_waves_per_eu(2,2)
// moved the RA budget off ~88 VGPRs; the 64-reg weight array was spilled
// before the t-loop and re-fetched 130 KB/step from scratch (FETCH 266 MB,
// WRITE only hout). Fix: shrink demand below the budget instead of raising
// the budget. 1024 threads / 16 waves -> wave owns 32 gates = 2 row-tiles
// x 4 k-tiles -> afrag is 8 x half8 = 32 VGPRs; total ~80 regs < 88.
//
// Wave w owns gates [32w, 32w+32). h broadcast via LDS as f16: ALL 16 B
// columns identical, so every C column computes the same dot (B n-mapping
// irrelevant; k-permutation cancels A-vs-B). Gate type = wave>>2.
// Pre-activation added AFTER the MFMA (additive const), one float4/lane.
// ---------------------------------------------------------------------------
template<bool IS_L0>
__global__ __launch_bounds__(1024)
__attribute__((amdgpu_waves_per_eu(4, 4)))
void lstm_rec_mfma(const float* __restrict__ Whh,   // (512,128) row-major
                   const float* __restrict__ xin,   // L0: x (T,128) ; L1: G (T,512)
                   const float* __restrict__ wih0,  // L0 only (512,)
                   const float* __restrict__ bih,   // L0 only
                   const float* __restrict__ bhh,   // L0 only
                   float* __restrict__ hout)        // (T,128)
{
    const int tid  = threadIdx.x;
    const int wave = tid >> 6;         // 0..15
    const int lane = tid & 63;
    const int quad = lane >> 4;
    const int col  = lane & 15;
    const int jb0  = wave * 32;        // first gate of this wave
    const int rm   = col & 1;          // row-tile this lane activates
    const int jm   = jb0 + rm * 16 + quad * 4;  // first of 4 gates this lane activates

    __shared__ __align__(16) _Float16 h16[HID];
    __shared__ __align__(16) float    gact[G4];

    // A fragments: afrag[r][kt] = A[m = jb0 + r*16 + col][k = kt*32 + quad*8 + j]
    half8 afrag[2][4];
    #pragma unroll
    for (int r = 0; r < 2; ++r) {
        const float* row = Whh + (size_t)(jb0 + r * 16 + col) * HID;
        #pragma unroll
        for (int kt = 0; kt < 4; ++kt) {
            const float4* p = reinterpret_cast<const float4*>(row + kt * 32 + quad * 8);
            float4 lo = p[0], hi = p[1];
            half8 h;
            h[0] = (_Float16)lo.x; h[1] = (_Float16)lo.y;
            h[2] = (_Float16)lo.z; h[3] = (_Float16)lo.w;
            h[4] = (_Float16)hi.x; h[5] = (_Float16)hi.y;
            h[6] = (_Float16)hi.z; h[7] = (_Float16)hi.w;
            afrag[r][kt] = h;
        }
    }

    // L0 constants for THIS lane's activation slice only (8 regs)
    f32x4 bsel = {0,0,0,0}, wsel = {0,0,0,0};
    if (IS_L0) {
        bsel = ld4(bih + jm) + ld4(bhh + jm);
        wsel = ld4(wih0 + jm);
    }

    // pin loop-invariants (defeat remat)
    #pragma unroll
    for (int r = 0; r < 2; ++r)
        #pragma unroll
        for (int kt = 0; kt < 4; ++kt) asm volatile("" : "+v"(afrag[r][kt]));
    if (IS_L0) asm volatile("" : "+v"(bsel), "+v"(wsel));

    float c_reg = 0.0f;
    if (tid < HID) h16[tid] = (_Float16)0.0f;
    __syncthreads();

    // pre-activation pipeline: one float4 per lane per step
    f32x4 pre_cur, pre_nxt;
    if (IS_L0) pre_cur = bsel + wsel * xin[HID - 1];
    else       pre_cur = ld4(xin + jm);

    const bool is_tanh_wave = ((wave >> 2) == 2);   // gates 256..383 = cell input

    for (int t = 0; t < T_STEPS; ++t) {
        // B fragments: every lane reads the same 8 f16 per k-tile (broadcast)
        half8 bfrag[4];
        #pragma unroll
        for (int kt = 0; kt < 4; ++kt)
            bfrag[kt] = *reinterpret_cast<const half8*>(&h16[kt * 32 + quad * 8]);

        // prefetch next step's pre-activation (hide L2 latency behind MFMA)
        const int tn = (t + 1 < T_STEPS) ? t + 1 : t;
        if (IS_L0) pre_nxt = bsel + wsel * xin[(size_t)tn * HID + HID - 1];
        else       pre_nxt = ld4(xin + (size_t)tn * G4 + jm);

        // D = Whh_tile @ h   (acc[r][reg] = gate jb0 + r*16 + quad*4 + reg)
        f32x4 acc[2] = {};
        #pragma unroll
        for (int kt = 0; kt < 4; ++kt) {
            #pragma unroll
            for (int r = 0; r < 2; ++r)
                acc[r] = __builtin_amdgcn_mfma_f32_16x16x32_f16(
                             afrag[r][kt], bfrag[kt], acc[r], 0, 0, 0);
        }

        // activation on this lane's slice (8 lanes/wave cover the 32 gates)
        f32x4 g = acc[rm] + pre_cur;
        f32x4 a4;
        if (is_tanh_wave) {
            a4[0] = fast_tanh(g[0]); a4[1] = fast_tanh(g[1]);
            a4[2] = fast_tanh(g[2]); a4[3] = fast_tanh(g[3]);
        } else {
            a4[0] = fast_sig(g[0]); a4[1] = fast_sig(g[1]);
            a4[2] = fast_sig(g[2]); a4[3] = fast_sig(g[3]);
        }
        if (col < 2)
            *reinterpret_cast<f32x4*>(&gact[jm]) = a4;
        __syncthreads();

        // serial tail: c/h update on 128 threads (waves 0-1)
        if (tid < HID) {
            float ai = gact[tid];
            float af = gact[tid + 128];
            float ag = gact[tid + 256];
            float ao = gact[tid + 384];
            c_reg = fmaf(af, c_reg, ai * ag);
            float h = ao * fast_tanh(c_reg);
            hout[(size_t)t * HID + tid] = h;
            h16[tid] = (_Float16)h;
        }
        pre_cur = pre_nxt;
        __syncthreads();
    }
}

// ---------------------------------------------------------------------------
// C[m,n] = sum_k A[m,k] * W[n,k] + b1[n] (+ b2[n])    K = 128 fixed
// ---------------------------------------------------------------------------
#define BM 64
#define BN 64
__global__ __launch_bounds__(256)
void gemm_bias_kernel(const float* __restrict__ A,   // (M,128)
                      const float* __restrict__ W,   // (N,128)
                      const float* __restrict__ b1,
                      const float* __restrict__ b2,  // may be null
                      float* __restrict__ C,         // (M,N)
                      int M, int N)
{
    __shared__ float Al[128][BM + 4];
    __shared__ float Wl[128][BN + 4];
    const int tid    = threadIdx.x;
    const int m_base = blockIdx.x * BM;
    const int n_base = blockIdx.y * BN;

    {
        const int r  = tid >> 2;          // 0..63
        const int kq = (tid & 3) * 32;    // 0,32,64,96
        const float4* srcA = reinterpret_cast<const float4*>(A + (size_t)(m_base + r) * 128 + kq);
        #pragma unroll
        for (int i = 0; i < 8; ++i) {
            float4 v = srcA[i];
            int k = kq + 4 * i;
            Al[k + 0][r] = v.x; Al[k + 1][r] = v.y; Al[k + 2][r] = v.z; Al[k + 3][r] = v.w;
        }
        const float4* srcW = reinterpret_cast<const float4*>(W + (size_t)(n_base + r) * 128 + kq);
        #pragma unroll
        for (int i = 0; i < 8; ++i) {
            float4 v = srcW[i];
            int k = kq + 4 * i;
            Wl[k + 0][r] = v.x; Wl[k + 1][r] = v.y; Wl[k + 2][r] = v.z; Wl[k + 3][r] = v.w;
        }
    }
    __syncthreads();

    const int tm = (tid & 15) * 4;
    const int tn = (tid >> 4) * 4;
    float acc[4][4] = {};
    #pragma unroll 8
    for (int k = 0; k < 128; ++k) {
        float4 av = *reinterpret_cast<const float4*>(&Al[k][tm]);
        float4 wv = *reinterpret_cast<const float4*>(&Wl[k][tn]);
        acc[0][0] = fmaf(av.x, wv.x, acc[0][0]);
        acc[0][1] = fmaf(av.x, wv.y, acc[0][1]);
        acc[0][2] = fmaf(av.x, wv.z, acc[0][2]);
        acc[0][3] = fmaf(av.x, wv.w, acc[0][3]);
        acc[1][0] = fmaf(av.y, wv.x, acc[1][0]);
        acc[1][1] = fmaf(av.y, wv.y, acc[1][1]);
        acc[1][2] = fmaf(av.y, wv.z, acc[1][2]);
        acc[1][3] = fmaf(av.y, wv.w, acc[1][3]);
        acc[2][0] = fmaf(av.z, wv.x, acc[2][0]);
        acc[2][1] = fmaf(av.z, wv.y, acc[2][1]);
        acc[2][2] = fmaf(av.z, wv.z, acc[2][2]);
        acc[2][3] = fmaf(av.z, wv.w, acc[2][3]);
        acc[3][0] = fmaf(av.w, wv.x, acc[3][0]);
        acc[3][1] = fmaf(av.w, wv.y, acc[3][1]);
        acc[3][2] = fmaf(av.w, wv.z, acc[3][2]);
        acc[3][3] = fmaf(av.w, wv.w, acc[3][3]);
    }

    float bias[4];
    #pragma unroll
    for (int i = 0; i < 4; ++i) {
        int n = n_base + tn + i;
        bias[i] = b1[n] + (b2 ? b2[n] : 0.0f);
    }
    #pragma unroll
    for (int mi = 0; mi < 4; ++mi) {
        float4 o;
        o.x = acc[mi][0] + bias[0];
        o.y = acc[mi][1] + bias[1];
        o.z = acc[mi][2] + bias[2];
        o.w = acc[mi][3] + bias[3];
        *reinterpret_cast<float4*>(C + (size_t)(m_base + tm + mi) * N + n_base + tn) = o;
    }
}

// ---------------------------------------------------------------------------
__global__ __launch_bounds__(512)
void bn_stats_kernel(const float* __restrict__ Z,       // (T,128)
                     const float* __restrict__ gamma,
                     const float* __restrict__ beta,
                     float* __restrict__ scale,
                     float* __restrict__ shift)
{
    const int tid = threadIdx.x;
    const int col = tid & 127;
    const int seg = tid >> 7;     // 0..3
    float s = 0.f, sq = 0.f;
    for (int t = seg * 512; t < (seg + 1) * 512; ++t) {
        float v = Z[(size_t)t * 128 + col];
        s += v;
        sq = fmaf(v, v, sq);
    }
    __shared__ float ps[4][128], pq[4][128];
    ps[seg][col] = s;
    pq[seg][col] = sq;
    __syncthreads();
    if (tid < 128) {
        float sum = ps[0][tid] + ps[1][tid] + ps[2][tid] + ps[3][tid];
        float sqq = pq[0][tid] + pq[1][tid] + pq[2][tid] + pq[3][tid];
        float mean = sum * (1.0f / 2048.0f);
        float var  = sqq * (1.0f / 2048.0f) - mean * mean;
        float sc = gamma[tid] * rsqrtf(var + 1e-5f);
        scale[tid] = sc;
        shift[tid] = beta[tid] - mean * sc;
    }
}

// ---------------------------------------------------------------------------
__global__ __launch_bounds__(512)
void fc2_kernel(const float* __restrict__ Z,      // (T,128)
                const float* __restrict__ scale,
                const float* __restrict__ shift,
                const float* __restrict__ fc2_w,  // (8,128)
                const float* __restrict__ fc2_b,
                float* __restrict__ out)          // (T,8)
{
    const int gid = blockIdx.x * blockDim.x + threadIdx.x;   // 0..16383
    const int o = gid & 7;
    const int t = gid >> 3;

    __shared__ float w_s[8][132];
    __shared__ float sc_s[128], sh_s[128];
    for (int i = threadIdx.x; i < 1024; i += 512) w_s[i >> 7][i & 127] = fc2_w[i];
    if (threadIdx.x < 128) {
        sc_s[threadIdx.x] = scale[threadIdx.x];
        sh_s[threadIdx.x] = shift[threadIdx.x];
    }
    __syncthreads();

    float acc = fc2_b[o];
    const float* zrow = Z + (size_t)t * 128;
    #pragma unroll 4
    for (int k = 0; k < 128; ++k) {
        float zn = fmaf(zrow[k], sc_s[k], sh_s[k]);
        zn = fmaxf(zn, 0.0f);
        acc = fmaf(zn, w_s[o][k], acc);
    }
    out[gid] = acc;
}

// ---------------------------------------------------------------------------
extern "C" void kernel_launch(void* const* d_in, const int* in_sizes, int n_in,
                              void* d_out, int out_size, void* d_ws, size_t ws_size,
                              hipStream_t stream)
{
    const float* x     = (const float*)d_in[0];   // (2048,128,1)
    const float* Wih0  = (const float*)d_in[1];   // (512,1)
    const float* Whh0  = (const float*)d_in[2];   // (512,128)
    const float* bih0  = (const float*)d_in[3];
    const float* bhh0  = (const float*)d_in[4];
    const float* Wih1  = (const float*)d_in[5];   // (512,128)
    const float* Whh1  = (const float*)d_in[6];   // (512,128)
    const float* bih1  = (const float*)d_in[7];
    const float* bhh1  = (const float*)d_in[8];
    const float* fc1_w = (const float*)d_in[9];   // (128,128)
    const float* fc1_b = (const float*)d_in[10];
    const float* gamma = (const float*)d_in[11];
    const float* beta  = (const float*)d_in[12];
    const float* fc2_w = (const float*)d_in[13];  // (8,128)
    const float* fc2_b = (const float*)d_in[14];
    float* out = (float*)d_out;                    // (2048,8) fp32

    float* h1    = (float*)d_ws;            // 2048*128
    float* G     = h1  + T_STEPS * HID;     // 2048*512
    float* h2    = G   + T_STEPS * G4;      // 2048*128
    float* z     = h2  + T_STEPS * HID;     // 2048*128
    float* scale = z   + T_STEPS * HID;     // 128
    float* shift = scale + 128;             // 128

    // K1: layer-0 recurrence (only batch element 127 matters)
    lstm_rec_mfma<true><<<1, 1024, 0, stream>>>(Whh0, x, Wih0, bih0, bhh0, h1);

    // K2: layer-1 input GEMM: G[t,:] = h1[t,:] @ Wih1^T + (bih1+bhh1)
    dim3 g2(T_STEPS / BM, G4 / BN);
    gemm_bias_kernel<<<g2, 256, 0, stream>>>(h1, Wih1, bih1, bhh1, G, T_STEPS, G4);

    // K3: layer-1 recurrence consuming precomputed G
    lstm_rec_mfma<false><<<1, 1024, 0, stream>>>(Whh1, G, nullptr, nullptr, nullptr, h2);

    // K4a: z = h2 @ fc1^T + fc1_b
    dim3 g4(T_STEPS / BM, HID / BN);
    gemm_bias_kernel<<<g4, 256, 0, stream>>>(h2, fc1_w, fc1_b, nullptr, z, T_STEPS, HID);

    // K4b: batchnorm stats over T axis
    bn_stats_kernel<<<1, 512, 0, stream>>>(z, gamma, beta, scale, shift);

    // K4c: normalize + relu + fc2
    fc2_kernel<<<T_STEPS * 8 / 512, 512, 0, stream>>>(z, scale, shift, fc2_w, fc2_b, out);
}

// Round 5
// 3450.653 us; speedup vs baseline: 1.3776x; 1.3776x over previous
//
#include <hip/hip_runtime.h>
#include <math.h>

#define T_STEPS 2048
#define HID     128
#define G4      512   // 4*H

typedef _Float16 half8 __attribute__((ext_vector_type(8)));
typedef float    f32x4 __attribute__((ext_vector_type(4)));

__device__ __forceinline__ float fast_sig(float x) {
    return __fdividef(1.0f, 1.0f + __expf(-x));
}
__device__ __forceinline__ float fast_tanh(float x) {
    return fmaf(2.0f, __fdividef(1.0f, 1.0f + __expf(-2.0f * x)), -1.0f);
}
__device__ __forceinline__ f32x4 ld4(const float* p) {
    float4 v = *reinterpret_cast<const float4*>(p);
    f32x4 r; r[0] = v.x; r[1] = v.y; r[2] = v.z; r[3] = v.w; return r;
}

// ---------------------------------------------------------------------------
// MFMA LSTM recurrence, single live batch element (b = 127).
//
// ROUND 2-4 LESSON: the RA's occupancy heuristic scales its VGPR budget with
// achievable waves/CU (88 @ 512thr, 52 @ 1024thr) and spilled the weight
// fragments every time; FETCH_SIZE == afrag bytes * 2048 steps in all three
// rounds. __launch_bounds__ min-waves and amdgpu_waves_per_eu were both
// ignored. The one lever the backend demonstrably respects is LDS-bounded
// occupancy (m132: 64KB LDS -> 2 blocks/CU). So: a 60 KB dummy LDS pad caps
// occupancy at 2 WG/CU; with 256 threads (4 waves) that is 2 waves/EU ->
// 256-VGPR budget. Wave owns 128 gates = 8 row-tiles x 4 k-tiles; demand
// ~215 regs < 256. Grid is 1 WG, so the wasted LDS/occupancy is free.
//
// h broadcast via LDS as f16: ALL 16 B-columns identical, so every C column
// computes the same dot (B n-mapping irrelevant; k-permutation cancels
// A-vs-B). acc[r][reg] = gate jb0 + 16r + 4quad + reg, identical over col.
// Activation: lanes col<8 own row-tile r=col (unrolled select, no dynamic
// register indexing -> no scratch). Pre-activation added AFTER the MFMA.
// ---------------------------------------------------------------------------
template<bool IS_L0>
__global__ __launch_bounds__(256)
void lstm_rec_mfma(const float* __restrict__ Whh,   // (512,128) row-major
                   const float* __restrict__ xin,   // L0: x (T,128) ; L1: G (T,512)
                   const float* __restrict__ wih0,  // L0 only (512,)
                   const float* __restrict__ bih,   // L0 only
                   const float* __restrict__ bhh,   // L0 only
                   float* __restrict__ hout)        // (T,128)
{
    const int tid  = threadIdx.x;
    const int wave = tid >> 6;         // 0..3
    const int lane = tid & 63;
    const int quad = lane >> 4;
    const int col  = lane & 15;
    const int jb0  = wave * 128;       // first gate of this wave
    const int rm   = col & 7;          // row-tile this lane activates (col<8)
    const int jm   = jb0 + rm * 16 + quad * 4;  // first of 4 gates this lane activates

    __shared__ __align__(16) _Float16 h16[HID];
    __shared__ __align__(16) float    gact[G4];
    __shared__ char occupancy_pad[60 * 1024];   // caps occupancy at 2 WG/CU ->
                                                // 2 waves/EU -> 256-reg RA budget
    ((volatile char*)occupancy_pad)[tid] = 0;   // keep the pad alive

    // A fragments: afrag[r][kt] = A[m = jb0 + r*16 + col][k = kt*32 + quad*8 + j]
    half8 afrag[8][4];
    #pragma unroll
    for (int r = 0; r < 8; ++r) {
        const float* row = Whh + (size_t)(jb0 + r * 16 + col) * HID;
        #pragma unroll
        for (int kt = 0; kt < 4; ++kt) {
            const float4* p = reinterpret_cast<const float4*>(row + kt * 32 + quad * 8);
            float4 lo = p[0], hi = p[1];
            half8 h;
            h[0] = (_Float16)lo.x; h[1] = (_Float16)lo.y;
            h[2] = (_Float16)lo.z; h[3] = (_Float16)lo.w;
            h[4] = (_Float16)hi.x; h[5] = (_Float16)hi.y;
            h[6] = (_Float16)hi.z; h[7] = (_Float16)hi.w;
            afrag[r][kt] = h;
        }
    }

    // L0 constants for THIS lane's activation slice only (8 regs)
    f32x4 bsel = {0,0,0,0}, wsel = {0,0,0,0};
    if (IS_L0) {
        bsel = ld4(bih + jm) + ld4(bhh + jm);
        wsel = ld4(wih0 + jm);
    }

    // pin loop-invariants (defeat remat)
    #pragma unroll
    for (int r = 0; r < 8; ++r)
        #pragma unroll
        for (int kt = 0; kt < 4; ++kt) asm volatile("" : "+v"(afrag[r][kt]));
    if (IS_L0) asm volatile("" : "+v"(bsel), "+v"(wsel));

    float c_reg = 0.0f;
    if (tid < HID) h16[tid] = (_Float16)0.0f;
    __syncthreads();

    // pre-activation pipeline: one float4 per lane per step
    f32x4 pre_cur, pre_nxt;
    if (IS_L0) pre_cur = bsel + wsel * xin[HID - 1];
    else       pre_cur = ld4(xin + jm);

    const bool is_tanh_wave = (wave == 2);   // gates 256..383 = cell input

    for (int t = 0; t < T_STEPS; ++t) {
        // B fragments: every lane reads the same 8 f16 per k-tile (broadcast)
        half8 bfrag[4];
        #pragma unroll
        for (int kt = 0; kt < 4; ++kt)
            bfrag[kt] = *reinterpret_cast<const half8*>(&h16[kt * 32 + quad * 8]);

        // prefetch next step's pre-activation (hide L2 latency behind MFMA)
        const int tn = (t + 1 < T_STEPS) ? t + 1 : t;
        if (IS_L0) pre_nxt = bsel + wsel * xin[(size_t)tn * HID + HID - 1];
        else       pre_nxt = ld4(xin + (size_t)tn * G4 + jm);

        // D = Whh_tile @ h   (32 MFMA, 8 independent accumulator chains)
        f32x4 acc[8] = {};
        #pragma unroll
        for (int kt = 0; kt < 4; ++kt) {
            #pragma unroll
            for (int r = 0; r < 8; ++r)
                acc[r] = __builtin_amdgcn_mfma_f32_16x16x32_f16(
                             afrag[r][kt], bfrag[kt], acc[r], 0, 0, 0);
        }

        // activation on this lane's slice: unrolled select (no dynamic reg index)
        f32x4 g = {0,0,0,0};
        #pragma unroll
        for (int r = 0; r < 8; ++r)
            if (rm == r) g = acc[r] + pre_cur;
        f32x4 a4;
        if (is_tanh_wave) {
            a4[0] = fast_tanh(g[0]); a4[1] = fast_tanh(g[1]);
            a4[2] = fast_tanh(g[2]); a4[3] = fast_tanh(g[3]);
        } else {
            a4[0] = fast_sig(g[0]); a4[1] = fast_sig(g[1]);
            a4[2] = fast_sig(g[2]); a4[3] = fast_sig(g[3]);
        }
        if (col < 8)
            *reinterpret_cast<f32x4*>(&gact[jm]) = a4;
        __syncthreads();

        // serial tail: c/h update on 128 threads (waves 0-1)
        if (tid < HID) {
            float ai = gact[tid];
            float af = gact[tid + 128];
            float ag = gact[tid + 256];
            float ao = gact[tid + 384];
            c_reg = fmaf(af, c_reg, ai * ag);
            float h = ao * fast_tanh(c_reg);
            hout[(size_t)t * HID + tid] = h;
            h16[tid] = (_Float16)h;
        }
        pre_cur = pre_nxt;
        __syncthreads();
    }
}

// ---------------------------------------------------------------------------
// C[m,n] = sum_k A[m,k] * W[n,k] + b1[n] (+ b2[n])    K = 128 fixed
// ---------------------------------------------------------------------------
#define BM 64
#define BN 64
__global__ __launch_bounds__(256)
void gemm_bias_kernel(const float* __restrict__ A,   // (M,128)
                      const float* __restrict__ W,   // (N,128)
                      const float* __restrict__ b1,
                      const float* __restrict__ b2,  // may be null
                      float* __restrict__ C,         // (M,N)
                      int M, int N)
{
    __shared__ float Al[128][BM + 4];
    __shared__ float Wl[128][BN + 4];
    const int tid    = threadIdx.x;
    const int m_base = blockIdx.x * BM;
    const int n_base = blockIdx.y * BN;

    {
        const int r  = tid >> 2;          // 0..63
        const int kq = (tid & 3) * 32;    // 0,32,64,96
        const float4* srcA = reinterpret_cast<const float4*>(A + (size_t)(m_base + r) * 128 + kq);
        #pragma unroll
        for (int i = 0; i < 8; ++i) {
            float4 v = srcA[i];
            int k = kq + 4 * i;
            Al[k + 0][r] = v.x; Al[k + 1][r] = v.y; Al[k + 2][r] = v.z; Al[k + 3][r] = v.w;
        }
        const float4* srcW = reinterpret_cast<const float4*>(W + (size_t)(n_base + r) * 128 + kq);
        #pragma unroll
        for (int i = 0; i < 8; ++i) {
            float4 v = srcW[i];
            int k = kq + 4 * i;
            Wl[k + 0][r] = v.x; Wl[k + 1][r] = v.y; Wl[k + 2][r] = v.z; Wl[k + 3][r] = v.w;
        }
    }
    __syncthreads();

    const int tm = (tid & 15) * 4;
    const int tn = (tid >> 4) * 4;
    float acc[4][4] = {};
    #pragma unroll 8
    for (int k = 0; k < 128; ++k) {
        float4 av = *reinterpret_cast<const float4*>(&Al[k][tm]);
        float4 wv = *reinterpret_cast<const float4*>(&Wl[k][tn]);
        acc[0][0] = fmaf(av.x, wv.x, acc[0][0]);
        acc[0][1] = fmaf(av.x, wv.y, acc[0][1]);
        acc[0][2] = fmaf(av.x, wv.z, acc[0][2]);
        acc[0][3] = fmaf(av.x, wv.w, acc[0][3]);
        acc[1][0] = fmaf(av.y, wv.x, acc[1][0]);
        acc[1][1] = fmaf(av.y, wv.y, acc[1][1]);
        acc[1][2] = fmaf(av.y, wv.z, acc[1][2]);
        acc[1][3] = fmaf(av.y, wv.w, acc[1][3]);
        acc[2][0] = fmaf(av.z, wv.x, acc[2][0]);
        acc[2][1] = fmaf(av.z, wv.y, acc[2][1]);
        acc[2][2] = fmaf(av.z, wv.z, acc[2][2]);
        acc[2][3] = fmaf(av.z, wv.w, acc[2][3]);
        acc[3][0] = fmaf(av.w, wv.x, acc[3][0]);
        acc[3][1] = fmaf(av.w, wv.y, acc[3][1]);
        acc[3][2] = fmaf(av.w, wv.z, acc[3][2]);
        acc[3][3] = fmaf(av.w, wv.w, acc[3][3]);
    }

    float bias[4];
    #pragma unroll
    for (int i = 0; i < 4; ++i) {
        int n = n_base + tn + i;
        bias[i] = b1[n] + (b2 ? b2[n] : 0.0f);
    }
    #pragma unroll
    for (int mi = 0; mi < 4; ++mi) {
        float4 o;
        o.x = acc[mi][0] + bias[0];
        o.y = acc[mi][1] + bias[1];
        o.z = acc[mi][2] + bias[2];
        o.w = acc[mi][3] + bias[3];
        *reinterpret_cast<float4*>(C + (size_t)(m_base + tm + mi) * N + n_base + tn) = o;
    }
}

// ---------------------------------------------------------------------------
__global__ __launch_bounds__(512)
void bn_stats_kernel(const float* __restrict__ Z,       // (T,128)
                     const float* __restrict__ gamma,
                     const float* __restrict__ beta,
                     float* __restrict__ scale,
                     float* __restrict__ shift)
{
    const int tid = threadIdx.x;
    const int col = tid & 127;
    const int seg = tid >> 7;     // 0..3
    float s = 0.f, sq = 0.f;
    for (int t = seg * 512; t < (seg + 1) * 512; ++t) {
        float v = Z[(size_t)t * 128 + col];
        s += v;
        sq = fmaf(v, v, sq);
    }
    __shared__ float ps[4][128], pq[4][128];
    ps[seg][col] = s;
    pq[seg][col] = sq;
    __syncthreads();
    if (tid < 128) {
        float sum = ps[0][tid] + ps[1][tid] + ps[2][tid] + ps[3][tid];
        float sqq = pq[0][tid] + pq[1][tid] + pq[2][tid] + pq[3][tid];
        float mean = sum * (1.0f / 2048.0f);
        float var  = sqq * (1.0f / 2048.0f) - mean * mean;
        float sc = gamma[tid] * rsqrtf(var + 1e-5f);
        scale[tid] = sc;
        shift[tid] = beta[tid] - mean * sc;
    }
}

// ---------------------------------------------------------------------------
__global__ __launch_bounds__(512)
void fc2_kernel(const float* __restrict__ Z,      // (T,128)
                const float* __restrict__ scale,
                const float* __restrict__ shift,
                const float* __restrict__ fc2_w,  // (8,128)
                const float* __restrict__ fc2_b,
                float* __restrict__ out)          // (T,8)
{
    const int gid = blockIdx.x * blockDim.x + threadIdx.x;   // 0..16383
    const int o = gid & 7;
    const int t = gid >> 3;

    __shared__ float w_s[8][132];
    __shared__ float sc_s[128], sh_s[128];
    for (int i = threadIdx.x; i < 1024; i += 512) w_s[i >> 7][i & 127] = fc2_w[i];
    if (threadIdx.x < 128) {
        sc_s[threadIdx.x] = scale[threadIdx.x];
        sh_s[threadIdx.x] = shift[threadIdx.x];
    }
    __syncthreads();

    float acc = fc2_b[o];
    const float* zrow = Z + (size_t)t * 128;
    #pragma unroll 4
    for (int k = 0; k < 128; ++k) {
        float zn = fmaf(zrow[k], sc_s[k], sh_s[k]);
        zn = fmaxf(zn, 0.0f);
        acc = fmaf(zn, w_s[o][k], acc);
    }
    out[gid] = acc;
}

// ---------------------------------------------------------------------------
extern "C" void kernel_launch(void* const* d_in, const int* in_sizes, int n_in,
                              void* d_out, int out_size, void* d_ws, size_t ws_size,
                              hipStream_t stream)
{
    const float* x     = (const float*)d_in[0];   // (2048,128,1)
    const float* Wih0  = (const float*)d_in[1];   // (512,1)
    const float* Whh0  = (const float*)d_in[2];   // (512,128)
    const float* bih0  = (const float*)d_in[3];
    const float* bhh0  = (const float*)d_in[4];
    const float* Wih1  = (const float*)d_in[5];   // (512,128)
    const float* Whh1  = (const float*)d_in[6];   // (512,128)
    const float* bih1  = (const float*)d_in[7];
    const float* bhh1  = (const float*)d_in[8];
    const float* fc1_w = (const float*)d_in[9];   // (128,128)
    const float* fc1_b = (const float*)d_in[10];
    const float* gamma = (const float*)d_in[11];
    const float* beta  = (const float*)d_in[12];
    const float* fc2_w = (const float*)d_in[13];  // (8,128)
    const float* fc2_b = (const float*)d_in[14];
    float* out = (float*)d_out;                    // (2048,8) fp32

    float* h1    = (float*)d_ws;            // 2048*128
    float* G     = h1  + T_STEPS * HID;     // 2048*512
    float* h2    = G   + T_STEPS * G4;      // 2048*128
    float* z     = h2  + T_STEPS * HID;     // 2048*128
    float* scale = z   + T_STEPS * HID;     // 128
    float* shift = scale + 128;             // 128

    // K1: layer-0 recurrence (only batch element 127 matters)
    lstm_rec_mfma<true><<<1, 256, 0, stream>>>(Whh0, x, Wih0, bih0, bhh0, h1);

    // K2: layer-1 input GEMM: G[t,:] = h1[t,:] @ Wih1^T + (bih1+bhh1)
    dim3 g2(T_STEPS / BM, G4 / BN);
    gemm_bias_kernel<<<g2, 256, 0, stream>>>(h1, Wih1, bih1, bhh1, G, T_STEPS, G4);

    // K3: layer-1 recurrence consuming precomputed G
    lstm_rec_mfma<false><<<1, 256, 0, stream>>>(Whh1, G, nullptr, nullptr, nullptr, h2);

    // K4a: z = h2 @ fc1^T + fc1_b
    dim3 g4(T_STEPS / BM, HID / BN);
    gemm_bias_kernel<<<g4, 256, 0, stream>>>(h2, fc1_w, fc1_b, nullptr, z, T_STEPS, HID);

    // K4b: batchnorm stats over T axis
    bn_stats_kernel<<<1, 512, 0, stream>>>(z, gamma, beta, scale, shift);

    // K4c: normalize + relu + fc2
    fc2_kernel<<<T_STEPS * 8 / 512, 512, 0, stream>>>(z, scale, shift, fc2_w, fc2_b, out);
}